// Round 14
// baseline (398.037 us; speedup 1.0000x reference)
//
#include <hip/hip_runtime.h>
#include <hip/hip_bf16.h>

typedef __bf16 v8bf16 __attribute__((ext_vector_type(8)));
typedef __bf16 bf16x4 __attribute__((ext_vector_type(4)));
typedef float  f32x4  __attribute__((ext_vector_type(4)));

#define D_MODEL 2048
#define S_LEN   2048
#define NHEADS  32
#define NGROUPS 8
#define DK      64
#define NTOK    4096   // B*S
#define NQKV    3072   // 2048 + 512 + 512
// 0.125 (1/sqrt(64)) * log2(e): softmax done in base-2 domain
#define QSCALE  0.18033688011112042f

__device__ __forceinline__ void lds_load16(const void* g, void* l) {
  __builtin_amdgcn_global_load_lds(
      (__attribute__((address_space(1))) unsigned int*)g,
      (__attribute__((address_space(3))) unsigned int*)l, 16, 0, 0);
}

// XOR swizzle for [*][64] bf16 tiles (128B row stride): col ^= (row&7)<<3
__device__ __forceinline__ int sw64(int row, int col) {
  return row * 64 + (col ^ ((row & 7) << 3));
}

// ---------------- fp32 -> bf16 elementwise ----------------
__global__ __launch_bounds__(256)
void cvt_f32_bf16(const float* __restrict__ in, __bf16* __restrict__ out, int n) {
  int i = (blockIdx.x * 256 + threadIdx.x) * 4;
  if (i >= n) return;
  float4 v = *(const float4*)(in + i);
  bf16x4 o = { (__bf16)v.x, (__bf16)v.y, (__bf16)v.z, (__bf16)v.w };
  *(bf16x4*)(out + i) = o;
}

// ---------------- all 4 weight transposes in one launch (z-dispatch) ----------------
__global__ __launch_bounds__(256)
void transpose_cvt_all(const float* __restrict__ wq, const float* __restrict__ wk,
                       const float* __restrict__ wv, const float* __restrict__ wo,
                       __bf16* __restrict__ wqkvT, __bf16* __restrict__ woT) {
  __shared__ float tile[32][33];
  const int tx = threadIdx.x, ty = threadIdx.y;
  const float* in;
  __bf16* out;
  int C;
  const int z = blockIdx.z;
  if (z == 0)      { in = wq; out = wqkvT;              C = 2048; }
  else if (z == 1) { if (blockIdx.x >= 16) return; in = wk; out = wqkvT + 2048 * 2048; C = 512; }
  else if (z == 2) { if (blockIdx.x >= 16) return; in = wv; out = wqkvT + 2560 * 2048; C = 512; }
  else             { in = wo; out = woT;                C = 2048; }
  const int R = 2048;
  int c0 = blockIdx.x * 32, r0 = blockIdx.y * 32;
#pragma unroll
  for (int j = 0; j < 4; j++)
    tile[ty + 8 * j][tx] = in[(size_t)(r0 + ty + 8 * j) * C + c0 + tx];
  __syncthreads();
#pragma unroll
  for (int j = 0; j < 4; j++)
    out[(size_t)(c0 + ty + 8 * j) * R + r0 + tx] = (__bf16)tile[tx][ty + 8 * j];
}

// ---------------- bf16 [R][Csub] (ld=ldin) -> bf16 [Csub][R] (ld=ldout) ----------------
__global__ __launch_bounds__(256)
void transpose_bf16(const __bf16* __restrict__ in, __bf16* __restrict__ out,
                    int R, int C, int ldin, int ldout) {
  __shared__ __bf16 tile[32][33];
  int tx = threadIdx.x, ty = threadIdx.y;
  int c0 = blockIdx.x * 32, r0 = blockIdx.y * 32;
#pragma unroll
  for (int j = 0; j < 4; j++)
    tile[ty + 8 * j][tx] = in[(size_t)(r0 + ty + 8 * j) * ldin + c0 + tx];
  __syncthreads();
#pragma unroll
  for (int j = 0; j < 4; j++)
    out[(size_t)(c0 + ty + 8 * j) * ldout + r0 + tx] = tile[tx][ty + 8 * j];
}

// ---------------- 4-phase GEMM (r13, unchanged): C = A * BT^T + bias ----------------
template <int MODE, int BN>
__global__ __launch_bounds__(512, 1)
void gemm_big(const __bf16* __restrict__ A, const __bf16* __restrict__ BT,
              const float* __restrict__ b0, const float* __restrict__ b1,
              const float* __restrict__ b2,
              __bf16* __restrict__ Cb, float* __restrict__ Cf,
              int M, int N, int K) {
  constexpr int FN = BN / 64;
  __shared__ __bf16 Alds[2 * 256 * 64];
  __shared__ __bf16 Blds[3 * BN * 64];
  const int t = threadIdx.x;
  const int lane = t & 63, w = t >> 6;
  const int lr = lane & 15, lg = lane >> 4;
  const int wm = w >> 2, wn = w & 3;
  const int cpx = gridDim.x >> 3;
  const int swz = (blockIdx.x & 7) * cpx + (blockIdx.x >> 3);
  const int nbx = N / BN;
  const int m0 = (swz / nbx) * 256, n0 = (swz % nbx) * BN;
  const int scol = (((t & 7) ^ ((t >> 3) & 7)) << 3);

  const __bf16* Abase = A + (size_t)(m0 + (t >> 3)) * K + scol;
  const __bf16* Bbase = BT + (size_t)(n0 + (t >> 3)) * K + scol;

  auto stageA = [&](int tile, int c) {
    lds_load16(Abase + (size_t)(c * 64) * K + tile * 64,
               Alds + (tile & 1) * 16384 + c * 4096 + t * 8);
  };
  auto stageB = [&](int tile, int bi, int c) {
    lds_load16(Bbase + (size_t)(c * 64) * K + tile * 64,
               Blds + bi * (BN * 64) + c * 4096 + t * 8);
  };

  const f32x4 fz = {0.f, 0.f, 0.f, 0.f};
  f32x4 acc[8][FN];
#pragma unroll
  for (int fm = 0; fm < 8; fm++)
#pragma unroll
    for (int fn = 0; fn < FN; fn++) acc[fm][fn] = fz;

#pragma unroll
  for (int c = 0; c < 4; c++) stageA(0, c);
#pragma unroll
  for (int c = 0; c < FN; c++) stageB(0, 0, c);
  stageA(1, 0);
  stageA(1, 2);
#pragma unroll
  for (int c = 0; c < FN; c++) stageB(1, 1, c);

  int bcur = 0, bn1 = 1, bn2 = 2;
  for (int kt = 0; kt < 32; kt++) {
    if (kt < 31) {
      if constexpr (FN == 3) asm volatile("s_waitcnt vmcnt(5)" ::: "memory");
      else                   asm volatile("s_waitcnt vmcnt(4)" ::: "memory");
    } else {
      asm volatile("s_waitcnt vmcnt(0)" ::: "memory");
    }
    __builtin_amdgcn_s_barrier();
    __builtin_amdgcn_sched_barrier(0);

    const __bf16* Ab = Alds + (kt & 1) * 16384;
    const __bf16* Bb = Blds + bcur * (BN * 64);
    v8bf16 bfr[2][FN];

    // ---- phase 1: fmh=0, ks=0 ----
    {
#pragma unroll
      for (int fn = 0; fn < FN; fn++)
        bfr[0][fn] = *(const v8bf16*)&Bb[sw64(wn * (BN / 4) + fn * 16 + lr, lg * 8)];
      v8bf16 af[4];
#pragma unroll
      for (int j = 0; j < 4; j++)
        af[j] = *(const v8bf16*)&Ab[sw64(wm * 128 + j * 16 + lr, lg * 8)];
      if (kt < 31) stageA(kt + 1, 1);
      __builtin_amdgcn_s_barrier();
      __builtin_amdgcn_sched_barrier(0);
      __builtin_amdgcn_s_setprio(1);
#pragma unroll
      for (int j = 0; j < 4; j++)
#pragma unroll
        for (int fn = 0; fn < FN; fn++)
          acc[j][fn] = __builtin_amdgcn_mfma_f32_16x16x32_bf16(af[j], bfr[0][fn], acc[j][fn], 0, 0, 0);
      __builtin_amdgcn_s_setprio(0);
      __builtin_amdgcn_sched_barrier(0);
      __builtin_amdgcn_s_barrier();
    }
    // ---- phase 2: fmh=0, ks=1 ----
    {
#pragma unroll
      for (int fn = 0; fn < FN; fn++)
        bfr[1][fn] = *(const v8bf16*)&Bb[sw64(wn * (BN / 4) + fn * 16 + lr, 32 + lg * 8)];
      v8bf16 af[4];
#pragma unroll
      for (int j = 0; j < 4; j++)
        af[j] = *(const v8bf16*)&Ab[sw64(wm * 128 + j * 16 + lr, 32 + lg * 8)];
      if (kt < 31) stageA(kt + 1, 3);
      __builtin_amdgcn_s_barrier();
      __builtin_amdgcn_sched_barrier(0);
      __builtin_amdgcn_s_setprio(1);
#pragma unroll
      for (int j = 0; j < 4; j++)
#pragma unroll
        for (int fn = 0; fn < FN; fn++)
          acc[j][fn] = __builtin_amdgcn_mfma_f32_16x16x32_bf16(af[j], bfr[1][fn], acc[j][fn], 0, 0, 0);
      __builtin_amdgcn_s_setprio(0);
      __builtin_amdgcn_sched_barrier(0);
      __builtin_amdgcn_s_barrier();
    }
    // ---- phase 3: fmh=1, ks=0 ----
    {
      v8bf16 af[4];
#pragma unroll
      for (int j = 0; j < 4; j++)
        af[j] = *(const v8bf16*)&Ab[sw64(wm * 128 + 64 + j * 16 + lr, lg * 8)];
      if (kt < 30) { stageA(kt + 2, 0); stageB(kt + 2, bn2, 0); }
      __builtin_amdgcn_s_barrier();
      __builtin_amdgcn_sched_barrier(0);
      __builtin_amdgcn_s_setprio(1);
#pragma unroll
      for (int j = 0; j < 4; j++)
#pragma unroll
        for (int fn = 0; fn < FN; fn++)
          acc[4 + j][fn] = __builtin_amdgcn_mfma_f32_16x16x32_bf16(af[j], bfr[0][fn], acc[4 + j][fn], 0, 0, 0);
      __builtin_amdgcn_s_setprio(0);
      __builtin_amdgcn_sched_barrier(0);
      __builtin_amdgcn_s_barrier();
    }
    // ---- phase 4: fmh=1, ks=1 ----
    {
      v8bf16 af[4];
#pragma unroll
      for (int j = 0; j < 4; j++)
        af[j] = *(const v8bf16*)&Ab[sw64(wm * 128 + 64 + j * 16 + lr, 32 + lg * 8)];
      if (kt < 30) {
        stageA(kt + 2, 2);
        stageB(kt + 2, bn2, 1);
        if constexpr (FN == 3) stageB(kt + 2, bn2, 2);
      }
      __builtin_amdgcn_s_barrier();
      __builtin_amdgcn_sched_barrier(0);
      __builtin_amdgcn_s_setprio(1);
#pragma unroll
      for (int j = 0; j < 4; j++)
#pragma unroll
        for (int fn = 0; fn < FN; fn++)
          acc[4 + j][fn] = __builtin_amdgcn_mfma_f32_16x16x32_bf16(af[j], bfr[1][fn], acc[4 + j][fn], 0, 0, 0);
      __builtin_amdgcn_s_setprio(0);
      __builtin_amdgcn_sched_barrier(0);
    }

    int tmp = bcur; bcur = bn1; bn1 = bn2; bn2 = tmp;
  }

#pragma unroll
  for (int fn = 0; fn < FN; fn++) {
    int col = n0 + wn * (BN / 4) + fn * 16 + lr;
    float bias, scale = 1.0f;
    if (MODE == 0) {
      if (col < 2048)      { bias = b0[col];        scale = QSCALE; }
      else if (col < 2560) { bias = b1[col - 2048]; }
      else                 { bias = b2[col - 2560]; }
    } else {
      bias = b0[col];
    }
#pragma unroll
    for (int fm = 0; fm < 8; fm++)
#pragma unroll
      for (int r = 0; r < 4; r++) {
        int row = m0 + wm * 128 + fm * 16 + lg * 4 + r;
        float v = acc[fm][fn][r] + bias;
        if (MODE == 0) Cb[(size_t)row * N + col] = (__bf16)(v * scale);
        else           Cf[(size_t)row * N + col] = v;
      }
  }
}

// ---------------- GQA flash attention (V direct from global, K-only LDS) ----------------
// S^T = mfma(K,Q): packed P writes; row-sum via ones-MFMA.
// V (4MB total, XCD-clustered -> L2-resident) read as 8 global b128/tile into regs:
// removes V staging + 8 LDS reads/tile (m169 mechanism). K stays LDS (8-wave reuse).
__global__ __launch_bounds__(512, 4)
void attn_kernel(const __bf16* __restrict__ QKV, const __bf16* __restrict__ VT,
                 __bf16* __restrict__ ctx) {
  // 36KB: K buf0 0..4095, K buf1 4096..8191, P: per-wave [32][40] at 8192+w*1280
  __shared__ __bf16 smem[18432];
  const int t = threadIdx.x;
  const int lane = t & 63, w = t >> 6;
  const int lr = lane & 15, lg = lane >> 4;
  const int flat = blockIdx.y * 8 + blockIdx.x;
  const int swz = (flat & 7) * 64 + (flat >> 3);
  const int qt = swz & 7, bh = swz >> 3;
  const int b = bh >> 5, h = bh & 31, g = h >> 2;
  const int q0 = qt * 256;
  const int scol = (((t & 7) ^ ((t >> 3) & 7)) << 3);

  v8bf16 qa[2][2];
#pragma unroll
  for (int mi = 0; mi < 2; mi++)
#pragma unroll
    for (int dk2 = 0; dk2 < 2; dk2++)
      qa[mi][dk2] = *(const v8bf16*)(QKV +
          (size_t)(b * S_LEN + q0 + w * 32 + mi * 16 + lr) * NQKV + h * DK + dk2 * 32 + lg * 8);

  const __bf16* kp = QKV + (size_t)(b * S_LEN + (t >> 3)) * NQKV + D_MODEL + g * DK + scol;
  // per-lane V read base: row d = g*64 + nd*16 + lr, cols kt*64 + ks*32 + lg*8
  const __bf16* vgp = VT + (size_t)(g * DK + lr) * NTOK + b * S_LEN + lg * 8;

  lds_load16(kp, smem + t * 8);
  __syncthreads();

  const int kloff0 = lr * 64 + ((lg * 8) ^ ((lr & 7) << 3));
  const int kloff1 = lr * 64 + ((32 + lg * 8) ^ ((lr & 7) << 3));
  __bf16* Pw = smem + 8192 + w * 1280;  // [32][40]

  const __bf16 one1 = (__bf16)1.0f;
  const v8bf16 ones = { one1, one1, one1, one1, one1, one1, one1, one1 };
  const f32x4 fz = {0.f, 0.f, 0.f, 0.f};
  f32x4 o[2][4], o_sum[2];
  o_sum[0] = fz; o_sum[1] = fz;
#pragma unroll
  for (int mi = 0; mi < 2; mi++)
#pragma unroll
    for (int nd = 0; nd < 4; nd++) o[mi][nd] = fz;

#pragma unroll 2
  for (int kt = 0; kt < 32; kt++) {
    if (kt < 31) {
      lds_load16(kp + (size_t)64 * NQKV, smem + (((kt & 1) ^ 1) << 12) + t * 8);
      kp += (size_t)64 * NQKV;
    }
    // issue ks=0 V loads early (consumed after QK+softmax: ~600 cy cover, L2-hit ~200)
    v8bf16 vb0[4], vb1[4];
#pragma unroll
    for (int nd = 0; nd < 4; nd++)
      vb0[nd] = *(const v8bf16*)(vgp + nd * 16 * NTOK);

    const __bf16* Kb = smem + ((kt & 1) << 12);
    const __bf16* k0 = Kb + kloff0;
    const __bf16* k1 = Kb + kloff1;

    f32x4 st[4][2];
#pragma unroll
    for (int ni = 0; ni < 4; ni++) { st[ni][0] = fz; st[ni][1] = fz; }
    __builtin_amdgcn_s_setprio(1);
#pragma unroll
    for (int ni = 0; ni < 4; ni++) {
      v8bf16 kb = *(const v8bf16*)(k0 + ni * 1024);
      st[ni][0] = __builtin_amdgcn_mfma_f32_16x16x32_bf16(kb, qa[0][0], st[ni][0], 0, 0, 0);
      st[ni][1] = __builtin_amdgcn_mfma_f32_16x16x32_bf16(kb, qa[1][0], st[ni][1], 0, 0, 0);
    }
#pragma unroll
    for (int ni = 0; ni < 4; ni++) {
      v8bf16 kb = *(const v8bf16*)(k1 + ni * 1024);
      st[ni][0] = __builtin_amdgcn_mfma_f32_16x16x32_bf16(kb, qa[0][1], st[ni][0], 0, 0, 0);
      st[ni][1] = __builtin_amdgcn_mfma_f32_16x16x32_bf16(kb, qa[1][1], st[ni][1], 0, 0, 0);
    }
    __builtin_amdgcn_s_setprio(0);
    // issue ks=1 V loads (covered by ks=0 softmax+PV)
#pragma unroll
    for (int nd = 0; nd < 4; nd++)
      vb1[nd] = *(const v8bf16*)(vgp + nd * 16 * NTOK + 32);
    vgp += 64;

#pragma unroll
    for (int ks = 0; ks < 2; ks++) {
#pragma unroll
      for (int mi = 0; mi < 2; mi++)
#pragma unroll
        for (int ni2 = 0; ni2 < 2; ni2++) {
          f32x4 sv = st[2 * ks + ni2][mi];
          bf16x4 pk = { (__bf16)exp2f(sv[0]), (__bf16)exp2f(sv[1]),
                        (__bf16)exp2f(sv[2]), (__bf16)exp2f(sv[3]) };
          *(bf16x4*)(Pw + (mi * 16 + lr) * 40 + ni2 * 16 + lg * 4) = pk;
        }
      v8bf16 pa0 = *(const v8bf16*)(Pw + lr * 40 + lg * 8);
      v8bf16 pa1 = *(const v8bf16*)(Pw + (16 + lr) * 40 + lg * 8);
      __builtin_amdgcn_s_setprio(1);
#pragma unroll
      for (int nd = 0; nd < 4; nd++) {
        v8bf16 vb = ks ? vb1[nd] : vb0[nd];
        o[0][nd] = __builtin_amdgcn_mfma_f32_16x16x32_bf16(pa0, vb, o[0][nd], 0, 0, 0);
        o[1][nd] = __builtin_amdgcn_mfma_f32_16x16x32_bf16(pa1, vb, o[1][nd], 0, 0, 0);
      }
      o_sum[0] = __builtin_amdgcn_mfma_f32_16x16x32_bf16(pa0, ones, o_sum[0], 0, 0, 0);
      o_sum[1] = __builtin_amdgcn_mfma_f32_16x16x32_bf16(pa1, ones, o_sum[1], 0, 0, 0);
      __builtin_amdgcn_s_setprio(0);
    }

    __syncthreads();  // drains K prefetch + protects K buffer swap
  }

#pragma unroll
  for (int mi = 0; mi < 2; mi++)
#pragma unroll
    for (int r = 0; r < 4; r++) {
      float inv = 1.0f / o_sum[mi][r];
      int row = b * S_LEN + q0 + w * 32 + mi * 16 + lg * 4 + r;
#pragma unroll
      for (int nd = 0; nd < 4; nd++)
        ctx[(size_t)row * D_MODEL + h * DK + nd * 16 + lr] = (__bf16)(o[mi][nd][r] * inv);
    }
}

extern "C" void kernel_launch(void* const* d_in, const int* in_sizes, int n_in,
                              void* d_out, int out_size, void* d_ws, size_t ws_size,
                              hipStream_t stream) {
  (void)in_sizes; (void)n_in; (void)out_size; (void)ws_size;
  const float* x  = (const float*)d_in[0];
  const float* wq = (const float*)d_in[1];
  const float* bq = (const float*)d_in[2];
  const float* wk = (const float*)d_in[3];
  const float* bk = (const float*)d_in[4];
  const float* wv = (const float*)d_in[5];
  const float* bv = (const float*)d_in[6];
  const float* wo = (const float*)d_in[7];
  const float* bo = (const float*)d_in[8];

  char* ws = (char*)d_ws;
  __bf16* xb    = (__bf16*)(ws);                 // [4096][2048]   16 MB
  __bf16* wqkvT = (__bf16*)(ws + 16777216);      // [3072][2048]   12 MB
  __bf16* woT   = (__bf16*)(ws + 29360128);      // [2048][2048]    8 MB
  __bf16* QKVb  = (__bf16*)(ws + 37748736);      // [4096][3072]   24 MB
  __bf16* VbT   = (__bf16*)(ws + 62914560);      // [512][4096]     4 MB
  __bf16* ctx   = (__bf16*)(ws + 67108864);      // [4096][2048]   16 MB

  dim3 tb(32, 8);
  cvt_f32_bf16<<<8192, 256, 0, stream>>>(x, xb, NTOK * D_MODEL);
  transpose_cvt_all<<<dim3(64, 64, 4), tb, 0, stream>>>(wq, wk, wv, wo, wqkvT, woT);

  gemm_big<0, 192><<<dim3(256), 512, 0, stream>>>(xb, wqkvT, bq, bk, bv,
                                                  QKVb, nullptr, NTOK, NQKV, 2048);
  transpose_bf16<<<dim3(16, 128), tb, 0, stream>>>(QKVb + 2560, VbT, 4096, 512, 3072, 4096);
  attn_kernel<<<dim3(8, 64), 512, 0, stream>>>(QKVb, VbT, ctx);
  gemm_big<1, 128><<<dim3(256), 512, 0, stream>>>(ctx, woT, bo, nullptr, nullptr,
                                                  nullptr, (float*)d_out, NTOK, 2048, 2048);
}

// Round 15
// 250.669 us; speedup vs baseline: 1.5879x; 1.5879x over previous
//
#include <hip/hip_runtime.h>
#include <hip/hip_bf16.h>

typedef __bf16 v8bf16 __attribute__((ext_vector_type(8)));
typedef __bf16 bf16x4 __attribute__((ext_vector_type(4)));
typedef float  f32x4  __attribute__((ext_vector_type(4)));
typedef float  f32x16 __attribute__((ext_vector_type(16)));

#define D_MODEL 2048
#define S_LEN   2048
#define NHEADS  32
#define NGROUPS 8
#define DK      64
#define NTOK    4096   // B*S
#define NQKV    3072   // 2048 + 512 + 512
// 0.125 (1/sqrt(64)) * log2(e): softmax done in base-2 domain
#define QSCALE  0.18033688011112042f

__device__ __forceinline__ void lds_load16(const void* g, void* l) {
  __builtin_amdgcn_global_load_lds(
      (__attribute__((address_space(1))) unsigned int*)g,
      (__attribute__((address_space(3))) unsigned int*)l, 16, 0, 0);
}

// XOR swizzle for [*][64] bf16 tiles (128B row stride): col ^= (row&7)<<3
__device__ __forceinline__ int sw64(int row, int col) {
  return row * 64 + (col ^ ((row & 7) << 3));
}

// ---------------- fp32 -> bf16 elementwise ----------------
__global__ __launch_bounds__(256)
void cvt_f32_bf16(const float* __restrict__ in, __bf16* __restrict__ out, int n) {
  int i = (blockIdx.x * 256 + threadIdx.x) * 4;
  if (i >= n) return;
  float4 v = *(const float4*)(in + i);
  bf16x4 o = { (__bf16)v.x, (__bf16)v.y, (__bf16)v.z, (__bf16)v.w };
  *(bf16x4*)(out + i) = o;
}

// ---------------- all 4 weight transposes in one launch (z-dispatch) ----------------
__global__ __launch_bounds__(256)
void transpose_cvt_all(const float* __restrict__ wq, const float* __restrict__ wk,
                       const float* __restrict__ wv, const float* __restrict__ wo,
                       __bf16* __restrict__ wqkvT, __bf16* __restrict__ woT) {
  __shared__ float tile[32][33];
  const int tx = threadIdx.x, ty = threadIdx.y;
  const float* in;
  __bf16* out;
  int C;
  const int z = blockIdx.z;
  if (z == 0)      { in = wq; out = wqkvT;              C = 2048; }
  else if (z == 1) { if (blockIdx.x >= 16) return; in = wk; out = wqkvT + 2048 * 2048; C = 512; }
  else if (z == 2) { if (blockIdx.x >= 16) return; in = wv; out = wqkvT + 2560 * 2048; C = 512; }
  else             { in = wo; out = woT;                C = 2048; }
  const int R = 2048;
  int c0 = blockIdx.x * 32, r0 = blockIdx.y * 32;
#pragma unroll
  for (int j = 0; j < 4; j++)
    tile[ty + 8 * j][tx] = in[(size_t)(r0 + ty + 8 * j) * C + c0 + tx];
  __syncthreads();
#pragma unroll
  for (int j = 0; j < 4; j++)
    out[(size_t)(c0 + ty + 8 * j) * R + r0 + tx] = (__bf16)tile[tx][ty + 8 * j];
}

// ---------------- bf16 [R][Csub] (ld=ldin) -> bf16 [Csub][R] (ld=ldout) ----------------
__global__ __launch_bounds__(256)
void transpose_bf16(const __bf16* __restrict__ in, __bf16* __restrict__ out,
                    int R, int C, int ldin, int ldout) {
  __shared__ __bf16 tile[32][33];
  int tx = threadIdx.x, ty = threadIdx.y;
  int c0 = blockIdx.x * 32, r0 = blockIdx.y * 32;
#pragma unroll
  for (int j = 0; j < 4; j++)
    tile[ty + 8 * j][tx] = in[(size_t)(r0 + ty + 8 * j) * ldin + c0 + tx];
  __syncthreads();
#pragma unroll
  for (int j = 0; j < 4; j++)
    out[(size_t)(c0 + ty + 8 * j) * ldout + r0 + tx] = tile[tx][ty + 8 * j];
}

// ---------------- 4-phase GEMM (r13, unchanged): C = A * BT^T + bias ----------------
template <int MODE, int BN>
__global__ __launch_bounds__(512, 1)
void gemm_big(const __bf16* __restrict__ A, const __bf16* __restrict__ BT,
              const float* __restrict__ b0, const float* __restrict__ b1,
              const float* __restrict__ b2,
              __bf16* __restrict__ Cb, float* __restrict__ Cf,
              int M, int N, int K) {
  constexpr int FN = BN / 64;
  __shared__ __bf16 Alds[2 * 256 * 64];
  __shared__ __bf16 Blds[3 * BN * 64];
  const int t = threadIdx.x;
  const int lane = t & 63, w = t >> 6;
  const int lr = lane & 15, lg = lane >> 4;
  const int wm = w >> 2, wn = w & 3;
  const int cpx = gridDim.x >> 3;
  const int swz = (blockIdx.x & 7) * cpx + (blockIdx.x >> 3);
  const int nbx = N / BN;
  const int m0 = (swz / nbx) * 256, n0 = (swz % nbx) * BN;
  const int scol = (((t & 7) ^ ((t >> 3) & 7)) << 3);

  const __bf16* Abase = A + (size_t)(m0 + (t >> 3)) * K + scol;
  const __bf16* Bbase = BT + (size_t)(n0 + (t >> 3)) * K + scol;

  auto stageA = [&](int tile, int c) {
    lds_load16(Abase + (size_t)(c * 64) * K + tile * 64,
               Alds + (tile & 1) * 16384 + c * 4096 + t * 8);
  };
  auto stageB = [&](int tile, int bi, int c) {
    lds_load16(Bbase + (size_t)(c * 64) * K + tile * 64,
               Blds + bi * (BN * 64) + c * 4096 + t * 8);
  };

  const f32x4 fz = {0.f, 0.f, 0.f, 0.f};
  f32x4 acc[8][FN];
#pragma unroll
  for (int fm = 0; fm < 8; fm++)
#pragma unroll
    for (int fn = 0; fn < FN; fn++) acc[fm][fn] = fz;

#pragma unroll
  for (int c = 0; c < 4; c++) stageA(0, c);
#pragma unroll
  for (int c = 0; c < FN; c++) stageB(0, 0, c);
  stageA(1, 0);
  stageA(1, 2);
#pragma unroll
  for (int c = 0; c < FN; c++) stageB(1, 1, c);

  int bcur = 0, bn1 = 1, bn2 = 2;
  for (int kt = 0; kt < 32; kt++) {
    if (kt < 31) {
      if constexpr (FN == 3) asm volatile("s_waitcnt vmcnt(5)" ::: "memory");
      else                   asm volatile("s_waitcnt vmcnt(4)" ::: "memory");
    } else {
      asm volatile("s_waitcnt vmcnt(0)" ::: "memory");
    }
    __builtin_amdgcn_s_barrier();
    __builtin_amdgcn_sched_barrier(0);

    const __bf16* Ab = Alds + (kt & 1) * 16384;
    const __bf16* Bb = Blds + bcur * (BN * 64);
    v8bf16 bfr[2][FN];

    // ---- phase 1: fmh=0, ks=0 ----
    {
#pragma unroll
      for (int fn = 0; fn < FN; fn++)
        bfr[0][fn] = *(const v8bf16*)&Bb[sw64(wn * (BN / 4) + fn * 16 + lr, lg * 8)];
      v8bf16 af[4];
#pragma unroll
      for (int j = 0; j < 4; j++)
        af[j] = *(const v8bf16*)&Ab[sw64(wm * 128 + j * 16 + lr, lg * 8)];
      if (kt < 31) stageA(kt + 1, 1);
      __builtin_amdgcn_s_barrier();
      __builtin_amdgcn_sched_barrier(0);
      __builtin_amdgcn_s_setprio(1);
#pragma unroll
      for (int j = 0; j < 4; j++)
#pragma unroll
        for (int fn = 0; fn < FN; fn++)
          acc[j][fn] = __builtin_amdgcn_mfma_f32_16x16x32_bf16(af[j], bfr[0][fn], acc[j][fn], 0, 0, 0);
      __builtin_amdgcn_s_setprio(0);
      __builtin_amdgcn_sched_barrier(0);
      __builtin_amdgcn_s_barrier();
    }
    // ---- phase 2: fmh=0, ks=1 ----
    {
#pragma unroll
      for (int fn = 0; fn < FN; fn++)
        bfr[1][fn] = *(const v8bf16*)&Bb[sw64(wn * (BN / 4) + fn * 16 + lr, 32 + lg * 8)];
      v8bf16 af[4];
#pragma unroll
      for (int j = 0; j < 4; j++)
        af[j] = *(const v8bf16*)&Ab[sw64(wm * 128 + j * 16 + lr, 32 + lg * 8)];
      if (kt < 31) stageA(kt + 1, 3);
      __builtin_amdgcn_s_barrier();
      __builtin_amdgcn_sched_barrier(0);
      __builtin_amdgcn_s_setprio(1);
#pragma unroll
      for (int j = 0; j < 4; j++)
#pragma unroll
        for (int fn = 0; fn < FN; fn++)
          acc[j][fn] = __builtin_amdgcn_mfma_f32_16x16x32_bf16(af[j], bfr[1][fn], acc[j][fn], 0, 0, 0);
      __builtin_amdgcn_s_setprio(0);
      __builtin_amdgcn_sched_barrier(0);
      __builtin_amdgcn_s_barrier();
    }
    // ---- phase 3: fmh=1, ks=0 ----
    {
      v8bf16 af[4];
#pragma unroll
      for (int j = 0; j < 4; j++)
        af[j] = *(const v8bf16*)&Ab[sw64(wm * 128 + 64 + j * 16 + lr, lg * 8)];
      if (kt < 30) { stageA(kt + 2, 0); stageB(kt + 2, bn2, 0); }
      __builtin_amdgcn_s_barrier();
      __builtin_amdgcn_sched_barrier(0);
      __builtin_amdgcn_s_setprio(1);
#pragma unroll
      for (int j = 0; j < 4; j++)
#pragma unroll
        for (int fn = 0; fn < FN; fn++)
          acc[4 + j][fn] = __builtin_amdgcn_mfma_f32_16x16x32_bf16(af[j], bfr[0][fn], acc[4 + j][fn], 0, 0, 0);
      __builtin_amdgcn_s_setprio(0);
      __builtin_amdgcn_sched_barrier(0);
      __builtin_amdgcn_s_barrier();
    }
    // ---- phase 4: fmh=1, ks=1 ----
    {
      v8bf16 af[4];
#pragma unroll
      for (int j = 0; j < 4; j++)
        af[j] = *(const v8bf16*)&Ab[sw64(wm * 128 + 64 + j * 16 + lr, 32 + lg * 8)];
      if (kt < 30) {
        stageA(kt + 2, 2);
        stageB(kt + 2, bn2, 1);
        if constexpr (FN == 3) stageB(kt + 2, bn2, 2);
      }
      __builtin_amdgcn_s_barrier();
      __builtin_amdgcn_sched_barrier(0);
      __builtin_amdgcn_s_setprio(1);
#pragma unroll
      for (int j = 0; j < 4; j++)
#pragma unroll
        for (int fn = 0; fn < FN; fn++)
          acc[4 + j][fn] = __builtin_amdgcn_mfma_f32_16x16x32_bf16(af[j], bfr[1][fn], acc[4 + j][fn], 0, 0, 0);
      __builtin_amdgcn_s_setprio(0);
      __builtin_amdgcn_sched_barrier(0);
    }

    int tmp = bcur; bcur = bn1; bn1 = bn2; bn2 = tmp;
  }

#pragma unroll
  for (int fn = 0; fn < FN; fn++) {
    int col = n0 + wn * (BN / 4) + fn * 16 + lr;
    float bias, scale = 1.0f;
    if (MODE == 0) {
      if (col < 2048)      { bias = b0[col];        scale = QSCALE; }
      else if (col < 2560) { bias = b1[col - 2048]; }
      else                 { bias = b2[col - 2560]; }
    } else {
      bias = b0[col];
    }
#pragma unroll
    for (int fm = 0; fm < 8; fm++)
#pragma unroll
      for (int r = 0; r < 4; r++) {
        int row = m0 + wm * 128 + fm * 16 + lg * 4 + r;
        float v = acc[fm][fn][r] + bias;
        if (MODE == 0) Cb[(size_t)row * N + col] = (__bf16)(v * scale);
        else           Cf[(size_t)row * N + col] = v;
      }
  }
}

// ---------------- GQA flash attention (32x32 swapped QK^T, in-register P) ----------------
// st = mfma(K, Q): C[key][q=lane&31] -> each lane holds P[q][32 keys] in regs.
// PV re-swapped: O^T = mfma(V^T_frag, P_frag); P B-operand assembled in-register
// via one __shfl_xor(32) + selects per dword pair (no P LDS roundtrip at all).
// Row-sum via ones-MFMA (all o_sum regs = rowsum(q)). Layouts verified by r9 run.
__global__ __launch_bounds__(512, 2)
void attn_kernel(const __bf16* __restrict__ QKV, const __bf16* __restrict__ VT,
                 __bf16* __restrict__ ctx) {
  // 32KB: buf0 {K:0..4095, VT:4096..8191}, buf1 {8192..16383}
  __shared__ __bf16 smem[16384];
  const int t = threadIdx.x;
  const int lane = t & 63, w = t >> 6;
  const int lc = lane & 31, hi = lane >> 5;
  const int flat = blockIdx.y * 8 + blockIdx.x;
  const int swz = (flat & 7) * 64 + (flat >> 3);
  const int qt = swz & 7, bh = swz >> 3;
  const int b = bh >> 5, h = bh & 31, g = h >> 2;
  const int q0 = qt * 256;
  const int scol = (((t & 7) ^ ((t >> 3) & 7)) << 3);

  // Q as B-operand: qb[m] = Q[q = q0+w*32+lc][d = m*16 + hi*8 .. +8]
  v8bf16 qb[4];
#pragma unroll
  for (int m = 0; m < 4; m++)
    qb[m] = *(const v8bf16*)(QKV +
        (size_t)(b * S_LEN + q0 + w * 32 + lc) * NQKV + h * DK + m * 16 + hi * 8);

  const __bf16* kp = QKV + (size_t)(b * S_LEN + (t >> 3)) * NQKV + D_MODEL + g * DK + scol;
  const __bf16* vp = VT + (size_t)(g * DK + (t >> 3)) * NTOK + b * S_LEN + scol;

  lds_load16(kp, smem + t * 8);
  lds_load16(vp, smem + 4096 + t * 8);
  __syncthreads();

  // loop-invariant swizzled column offsets (rows are lc-based, (row&7)==(lc&7))
  int coloff[4];
#pragma unroll
  for (int m = 0; m < 4; m++)
    coloff[m] = (m * 16 + hi * 8) ^ ((lc & 7) << 3);
  const int rowoff = lc * 64;

  const __bf16 one1 = (__bf16)1.0f;
  const v8bf16 ones = { one1, one1, one1, one1, one1, one1, one1, one1 };
  const f32x16 fz16 = {0.f,0.f,0.f,0.f,0.f,0.f,0.f,0.f,0.f,0.f,0.f,0.f,0.f,0.f,0.f,0.f};
  f32x16 o0 = fz16, o1 = fz16, osum = fz16;

  union U2 { __bf16 hh[2]; unsigned u; };

#pragma unroll 2
  for (int kt = 0; kt < 32; kt++) {
    if (kt < 31) {
      __bf16* nb = smem + (((kt & 1) ^ 1) << 13);
      lds_load16(kp + (size_t)64 * NQKV, nb + t * 8);
      lds_load16(vp + 64, nb + 4096 + t * 8);
      kp += (size_t)64 * NQKV;
      vp += 64;
    }
    const __bf16* Kb = smem + ((kt & 1) << 13);
    const __bf16* Vb = Kb + 4096;
    const __bf16* kb0 = Kb + rowoff;

    // QK^T swapped: st0 = C[keys 0..31][q=lc], st1 = C[keys 32..63][q=lc]
    f32x16 st0 = fz16, st1 = fz16;
    __builtin_amdgcn_s_setprio(1);
#pragma unroll
    for (int m = 0; m < 4; m++) {
      v8bf16 ka0 = *(const v8bf16*)(kb0 + coloff[m]);
      v8bf16 ka1 = *(const v8bf16*)(kb0 + 2048 + coloff[m]);
      st0 = __builtin_amdgcn_mfma_f32_32x32x16_bf16(ka0, qb[m], st0, 0, 0, 0);
      st1 = __builtin_amdgcn_mfma_f32_32x32x16_bf16(ka1, qb[m], st1, 0, 0, 0);
    }
    __builtin_amdgcn_s_setprio(0);

    // p = exp2(s) in place
#pragma unroll
    for (int r = 0; r < 16; r++) st0[r] = exp2f(st0[r]);
#pragma unroll
    for (int r = 0; r < 16; r++) st1[r] = exp2f(st1[r]);

    // per 16-key slice: assemble P B-fragment in-register, PV + ones-MFMA
#pragma unroll
    for (int s = 0; s < 4; s++) {
      const int base = 8 * (s & 1);
      unsigned d0[2], d2[2];
#pragma unroll
      for (int c = 0; c < 2; c++) {
        float a0, a1, a4, a5;
        if (s < 2) { a0 = st0[base+2*c]; a1 = st0[base+2*c+1]; a4 = st0[base+4+2*c]; a5 = st0[base+5+2*c]; }
        else       { a0 = st1[base+2*c]; a1 = st1[base+2*c+1]; a4 = st1[base+4+2*c]; a5 = st1[base+5+2*c]; }
        U2 Y, Z;
        Y.hh[0] = (__bf16)a0; Y.hh[1] = (__bf16)a1;
        Z.hh[0] = (__bf16)a4; Z.hh[1] = (__bf16)a5;
        unsigned G = hi ? Y.u : Z.u;          // what the other half needs from me
        unsigned sG = __shfl_xor(G, 32, 64);
        d0[c] = hi ? sG : Y.u;                // keys j=2c,2c+1   (owner half 0)
        d2[c] = hi ? Z.u : sG;                // keys j=4+2c,5+2c (owner half 1)
      }
      union { v8bf16 v; unsigned u[4]; } pa;
      pa.u[0] = d0[0]; pa.u[1] = d0[1]; pa.u[2] = d2[0]; pa.u[3] = d2[1];

      // V^T A-frags: va[dt] = VT[d = dt*32+lc][key = s*16 + hi*8 .. +8]
      const int vcol = (s * 16 + hi * 8) ^ ((lc & 7) << 3);
      v8bf16 va0 = *(const v8bf16*)(Vb + rowoff + vcol);
      v8bf16 va1 = *(const v8bf16*)(Vb + 2048 + rowoff + vcol);
      __builtin_amdgcn_s_setprio(1);
      o0   = __builtin_amdgcn_mfma_f32_32x32x16_bf16(va0, pa.v, o0, 0, 0, 0);
      o1   = __builtin_amdgcn_mfma_f32_32x32x16_bf16(va1, pa.v, o1, 0, 0, 0);
      osum = __builtin_amdgcn_mfma_f32_32x32x16_bf16(ones, pa.v, osum, 0, 0, 0);
      __builtin_amdgcn_s_setprio(0);
    }

    __syncthreads();  // drains prefetch vmcnt + protects buffer swap
  }

  // epilogue: o holds O^T fragments C[d][q=lc]; osum regs all equal rowsum(q=lc)
  const float inv = 1.0f / osum[0];
  const int row = b * S_LEN + q0 + w * 32 + lc;
#pragma unroll
  for (int rr = 0; rr < 4; rr++) {
    bf16x4 pk0 = { (__bf16)(o0[4*rr+0]*inv), (__bf16)(o0[4*rr+1]*inv),
                   (__bf16)(o0[4*rr+2]*inv), (__bf16)(o0[4*rr+3]*inv) };
    bf16x4 pk1 = { (__bf16)(o1[4*rr+0]*inv), (__bf16)(o1[4*rr+1]*inv),
                   (__bf16)(o1[4*rr+2]*inv), (__bf16)(o1[4*rr+3]*inv) };
    *(bf16x4*)(ctx + (size_t)row * D_MODEL + h * DK + rr * 8 + hi * 4)      = pk0;
    *(bf16x4*)(ctx + (size_t)row * D_MODEL + h * DK + 32 + rr * 8 + hi * 4) = pk1;
  }
}

extern "C" void kernel_launch(void* const* d_in, const int* in_sizes, int n_in,
                              void* d_out, int out_size, void* d_ws, size_t ws_size,
                              hipStream_t stream) {
  (void)in_sizes; (void)n_in; (void)out_size; (void)ws_size;
  const float* x  = (const float*)d_in[0];
  const float* wq = (const float*)d_in[1];
  const float* bq = (const float*)d_in[2];
  const float* wk = (const float*)d_in[3];
  const float* bk = (const float*)d_in[4];
  const float* wv = (const float*)d_in[5];
  const float* bv = (const float*)d_in[6];
  const float* wo = (const float*)d_in[7];
  const float* bo = (const float*)d_in[8];

  char* ws = (char*)d_ws;
  __bf16* xb    = (__bf16*)(ws);                 // [4096][2048]   16 MB
  __bf16* wqkvT = (__bf16*)(ws + 16777216);      // [3072][2048]   12 MB
  __bf16* woT   = (__bf16*)(ws + 29360128);      // [2048][2048]    8 MB
  __bf16* QKVb  = (__bf16*)(ws + 37748736);      // [4096][3072]   24 MB
  __bf16* VbT   = (__bf16*)(ws + 62914560);      // [512][4096]     4 MB
  __bf16* ctx   = (__bf16*)(ws + 67108864);      // [4096][2048]   16 MB

  dim3 tb(32, 8);
  cvt_f32_bf16<<<8192, 256, 0, stream>>>(x, xb, NTOK * D_MODEL);
  transpose_cvt_all<<<dim3(64, 64, 4), tb, 0, stream>>>(wq, wk, wv, wo, wqkvT, woT);

  gemm_big<0, 192><<<dim3(256), 512, 0, stream>>>(xb, wqkvT, bq, bk, bv,
                                                  QKVb, nullptr, NTOK, NQKV, 2048);
  transpose_bf16<<<dim3(16, 128), tb, 0, stream>>>(QKVb + 2560, VbT, 4096, 512, 3072, 4096);
  attn_kernel<<<dim3(8, 64), 512, 0, stream>>>(QKVb, VbT, ctx);
  gemm_big<1, 128><<<dim3(256), 512, 0, stream>>>(ctx, woT, bo, nullptr, nullptr,
                                                  nullptr, (float*)d_out, NTOK, 2048, 2048);
}

// Round 16
// 215.055 us; speedup vs baseline: 1.8509x; 1.1656x over previous
//
#include <hip/hip_runtime.h>
#include <hip/hip_bf16.h>

typedef __bf16 v8bf16 __attribute__((ext_vector_type(8)));
typedef __bf16 bf16x4 __attribute__((ext_vector_type(4)));
typedef float  f32x4  __attribute__((ext_vector_type(4)));

#define D_MODEL 2048
#define S_LEN   2048
#define NHEADS  32
#define NGROUPS 8
#define DK      64
#define NTOK    4096   // B*S
#define NQKV    3072   // 2048 + 512 + 512
// 0.125 (1/sqrt(64)) * log2(e): softmax done in base-2 domain
#define QSCALE  0.18033688011112042f

__device__ __forceinline__ void lds_load16(const void* g, void* l) {
  __builtin_amdgcn_global_load_lds(
      (__attribute__((address_space(1))) unsigned int*)g,
      (__attribute__((address_space(3))) unsigned int*)l, 16, 0, 0);
}

// XOR swizzle for [*][64] bf16 tiles (128B row stride): col ^= (row&7)<<3
__device__ __forceinline__ int sw64(int row, int col) {
  return row * 64 + (col ^ ((row & 7) << 3));
}

// ---------------- fp32 -> bf16 elementwise ----------------
__global__ __launch_bounds__(256)
void cvt_f32_bf16(const float* __restrict__ in, __bf16* __restrict__ out, int n) {
  int i = (blockIdx.x * 256 + threadIdx.x) * 4;
  if (i >= n) return;
  float4 v = *(const float4*)(in + i);
  bf16x4 o = { (__bf16)v.x, (__bf16)v.y, (__bf16)v.z, (__bf16)v.w };
  *(bf16x4*)(out + i) = o;
}

// ---------------- all 4 weight transposes in one launch (z-dispatch) ----------------
__global__ __launch_bounds__(256)
void transpose_cvt_all(const float* __restrict__ wq, const float* __restrict__ wk,
                       const float* __restrict__ wv, const float* __restrict__ wo,
                       __bf16* __restrict__ wqkvT, __bf16* __restrict__ woT) {
  __shared__ float tile[32][33];
  const int tx = threadIdx.x, ty = threadIdx.y;
  const float* in;
  __bf16* out;
  int C;
  const int z = blockIdx.z;
  if (z == 0)      { in = wq; out = wqkvT;              C = 2048; }
  else if (z == 1) { if (blockIdx.x >= 16) return; in = wk; out = wqkvT + 2048 * 2048; C = 512; }
  else if (z == 2) { if (blockIdx.x >= 16) return; in = wv; out = wqkvT + 2560 * 2048; C = 512; }
  else             { in = wo; out = woT;                C = 2048; }
  const int R = 2048;
  int c0 = blockIdx.x * 32, r0 = blockIdx.y * 32;
#pragma unroll
  for (int j = 0; j < 4; j++)
    tile[ty + 8 * j][tx] = in[(size_t)(r0 + ty + 8 * j) * C + c0 + tx];
  __syncthreads();
#pragma unroll
  for (int j = 0; j < 4; j++)
    out[(size_t)(c0 + ty + 8 * j) * R + r0 + tx] = (__bf16)tile[tx][ty + 8 * j];
}

// ---------------- 4-phase GEMM: C = A * BT^T + bias ----------------
// MODE 0 additionally writes the V block (cols >= 2560) TRANSPOSED into Vt
// ([512][4096], Vt[col-2560][row]) as packed bf16x4 row-quads -- this fuses the
// separate V-transpose kernel into the epilogue. Fragments are 16-col aligned,
// so the region branch is lane-uniform.
template <int MODE, int BN>
__global__ __launch_bounds__(512, 1)
void gemm_big(const __bf16* __restrict__ A, const __bf16* __restrict__ BT,
              const float* __restrict__ b0, const float* __restrict__ b1,
              const float* __restrict__ b2,
              __bf16* __restrict__ Cb, float* __restrict__ Cf,
              __bf16* __restrict__ Vt,
              int M, int N, int K) {
  constexpr int FN = BN / 64;
  __shared__ __bf16 Alds[2 * 256 * 64];
  __shared__ __bf16 Blds[3 * BN * 64];
  const int t = threadIdx.x;
  const int lane = t & 63, w = t >> 6;
  const int lr = lane & 15, lg = lane >> 4;
  const int wm = w >> 2, wn = w & 3;
  const int cpx = gridDim.x >> 3;
  const int swz = (blockIdx.x & 7) * cpx + (blockIdx.x >> 3);
  const int nbx = N / BN;
  const int m0 = (swz / nbx) * 256, n0 = (swz % nbx) * BN;
  const int scol = (((t & 7) ^ ((t >> 3) & 7)) << 3);

  const __bf16* Abase = A + (size_t)(m0 + (t >> 3)) * K + scol;
  const __bf16* Bbase = BT + (size_t)(n0 + (t >> 3)) * K + scol;

  auto stageA = [&](int tile, int c) {
    lds_load16(Abase + (size_t)(c * 64) * K + tile * 64,
               Alds + (tile & 1) * 16384 + c * 4096 + t * 8);
  };
  auto stageB = [&](int tile, int bi, int c) {
    lds_load16(Bbase + (size_t)(c * 64) * K + tile * 64,
               Blds + bi * (BN * 64) + c * 4096 + t * 8);
  };

  const f32x4 fz = {0.f, 0.f, 0.f, 0.f};
  f32x4 acc[8][FN];
#pragma unroll
  for (int fm = 0; fm < 8; fm++)
#pragma unroll
    for (int fn = 0; fn < FN; fn++) acc[fm][fn] = fz;

#pragma unroll
  for (int c = 0; c < 4; c++) stageA(0, c);
#pragma unroll
  for (int c = 0; c < FN; c++) stageB(0, 0, c);
  stageA(1, 0);
  stageA(1, 2);
#pragma unroll
  for (int c = 0; c < FN; c++) stageB(1, 1, c);

  int bcur = 0, bn1 = 1, bn2 = 2;
  for (int kt = 0; kt < 32; kt++) {
    if (kt < 31) {
      if constexpr (FN == 3) asm volatile("s_waitcnt vmcnt(5)" ::: "memory");
      else                   asm volatile("s_waitcnt vmcnt(4)" ::: "memory");
    } else {
      asm volatile("s_waitcnt vmcnt(0)" ::: "memory");
    }
    __builtin_amdgcn_s_barrier();
    __builtin_amdgcn_sched_barrier(0);

    const __bf16* Ab = Alds + (kt & 1) * 16384;
    const __bf16* Bb = Blds + bcur * (BN * 64);
    v8bf16 bfr[2][FN];

    // ---- phase 1: fmh=0, ks=0 ----
    {
#pragma unroll
      for (int fn = 0; fn < FN; fn++)
        bfr[0][fn] = *(const v8bf16*)&Bb[sw64(wn * (BN / 4) + fn * 16 + lr, lg * 8)];
      v8bf16 af[4];
#pragma unroll
      for (int j = 0; j < 4; j++)
        af[j] = *(const v8bf16*)&Ab[sw64(wm * 128 + j * 16 + lr, lg * 8)];
      if (kt < 31) stageA(kt + 1, 1);
      __builtin_amdgcn_s_barrier();
      __builtin_amdgcn_sched_barrier(0);
      __builtin_amdgcn_s_setprio(1);
#pragma unroll
      for (int j = 0; j < 4; j++)
#pragma unroll
        for (int fn = 0; fn < FN; fn++)
          acc[j][fn] = __builtin_amdgcn_mfma_f32_16x16x32_bf16(af[j], bfr[0][fn], acc[j][fn], 0, 0, 0);
      __builtin_amdgcn_s_setprio(0);
      __builtin_amdgcn_sched_barrier(0);
      __builtin_amdgcn_s_barrier();
    }
    // ---- phase 2: fmh=0, ks=1 ----
    {
#pragma unroll
      for (int fn = 0; fn < FN; fn++)
        bfr[1][fn] = *(const v8bf16*)&Bb[sw64(wn * (BN / 4) + fn * 16 + lr, 32 + lg * 8)];
      v8bf16 af[4];
#pragma unroll
      for (int j = 0; j < 4; j++)
        af[j] = *(const v8bf16*)&Ab[sw64(wm * 128 + j * 16 + lr, 32 + lg * 8)];
      if (kt < 31) stageA(kt + 1, 3);
      __builtin_amdgcn_s_barrier();
      __builtin_amdgcn_sched_barrier(0);
      __builtin_amdgcn_s_setprio(1);
#pragma unroll
      for (int j = 0; j < 4; j++)
#pragma unroll
        for (int fn = 0; fn < FN; fn++)
          acc[j][fn] = __builtin_amdgcn_mfma_f32_16x16x32_bf16(af[j], bfr[1][fn], acc[j][fn], 0, 0, 0);
      __builtin_amdgcn_s_setprio(0);
      __builtin_amdgcn_sched_barrier(0);
      __builtin_amdgcn_s_barrier();
    }
    // ---- phase 3: fmh=1, ks=0 ----
    {
      v8bf16 af[4];
#pragma unroll
      for (int j = 0; j < 4; j++)
        af[j] = *(const v8bf16*)&Ab[sw64(wm * 128 + 64 + j * 16 + lr, lg * 8)];
      if (kt < 30) { stageA(kt + 2, 0); stageB(kt + 2, bn2, 0); }
      __builtin_amdgcn_s_barrier();
      __builtin_amdgcn_sched_barrier(0);
      __builtin_amdgcn_s_setprio(1);
#pragma unroll
      for (int j = 0; j < 4; j++)
#pragma unroll
        for (int fn = 0; fn < FN; fn++)
          acc[4 + j][fn] = __builtin_amdgcn_mfma_f32_16x16x32_bf16(af[j], bfr[0][fn], acc[4 + j][fn], 0, 0, 0);
      __builtin_amdgcn_s_setprio(0);
      __builtin_amdgcn_sched_barrier(0);
      __builtin_amdgcn_s_barrier();
    }
    // ---- phase 4: fmh=1, ks=1 ----
    {
      v8bf16 af[4];
#pragma unroll
      for (int j = 0; j < 4; j++)
        af[j] = *(const v8bf16*)&Ab[sw64(wm * 128 + 64 + j * 16 + lr, 32 + lg * 8)];
      if (kt < 30) {
        stageA(kt + 2, 2);
        stageB(kt + 2, bn2, 1);
        if constexpr (FN == 3) stageB(kt + 2, bn2, 2);
      }
      __builtin_amdgcn_s_barrier();
      __builtin_amdgcn_sched_barrier(0);
      __builtin_amdgcn_s_setprio(1);
#pragma unroll
      for (int j = 0; j < 4; j++)
#pragma unroll
        for (int fn = 0; fn < FN; fn++)
          acc[4 + j][fn] = __builtin_amdgcn_mfma_f32_16x16x32_bf16(af[j], bfr[1][fn], acc[4 + j][fn], 0, 0, 0);
      __builtin_amdgcn_s_setprio(0);
      __builtin_amdgcn_sched_barrier(0);
    }

    int tmp = bcur; bcur = bn1; bn1 = bn2; bn2 = tmp;
  }

#pragma unroll
  for (int fn = 0; fn < FN; fn++) {
    int col = n0 + wn * (BN / 4) + fn * 16 + lr;
    if (MODE == 0 && col >= 2560) {
      // V block: write transposed into Vt[col-2560][row], 4 rows per packed store
      float bias = b2[col - 2560];
#pragma unroll
      for (int fm = 0; fm < 8; fm++) {
        int row0 = m0 + wm * 128 + fm * 16 + lg * 4;
        bf16x4 pk = { (__bf16)(acc[fm][fn][0] + bias), (__bf16)(acc[fm][fn][1] + bias),
                      (__bf16)(acc[fm][fn][2] + bias), (__bf16)(acc[fm][fn][3] + bias) };
        *(bf16x4*)(Vt + (size_t)(col - 2560) * NTOK + row0) = pk;
      }
      continue;
    }
    float bias, scale = 1.0f;
    if (MODE == 0) {
      if (col < 2048) { bias = b0[col]; scale = QSCALE; }
      else            { bias = b1[col - 2048]; }
    } else {
      bias = b0[col];
    }
#pragma unroll
    for (int fm = 0; fm < 8; fm++)
#pragma unroll
      for (int r = 0; r < 4; r++) {
        int row = m0 + wm * 128 + fm * 16 + lg * 4 + r;
        float v = acc[fm][fn][r] + bias;
        if (MODE == 0) Cb[(size_t)row * N + col] = (__bf16)(v * scale);
        else           Cf[(size_t)row * N + col] = v;
      }
  }
}

// ---------------- GQA flash attention (8 waves x 32 q, r13 best-measured) ----------------
// S^T = mfma(K,Q): lane holds 4 consecutive keys for fixed q -> packed P writes.
// Row-sum via MFMA with ones-vector (matrix pipe, not VALU).
__global__ __launch_bounds__(512, 2)
void attn_kernel(const __bf16* __restrict__ QKV, const __bf16* __restrict__ VT,
                 __bf16* __restrict__ ctx) {
  __shared__ __bf16 smem[26624];
  const int t = threadIdx.x;
  const int lane = t & 63, w = t >> 6;
  const int lr = lane & 15, lg = lane >> 4;
  const int flat = blockIdx.y * 8 + blockIdx.x;
  const int swz = (flat & 7) * 64 + (flat >> 3);
  const int qt = swz & 7, bh = swz >> 3;
  const int b = bh >> 5, h = bh & 31, g = h >> 2;
  const int q0 = qt * 256;
  const int scol = (((t & 7) ^ ((t >> 3) & 7)) << 3);

  v8bf16 qa[2][2];
#pragma unroll
  for (int mi = 0; mi < 2; mi++)
#pragma unroll
    for (int dk2 = 0; dk2 < 2; dk2++)
      qa[mi][dk2] = *(const v8bf16*)(QKV +
          (size_t)(b * S_LEN + q0 + w * 32 + mi * 16 + lr) * NQKV + h * DK + dk2 * 32 + lg * 8);

  const __bf16* kp = QKV + (size_t)(b * S_LEN + (t >> 3)) * NQKV + D_MODEL + g * DK + scol;
  const __bf16* vp = VT + (size_t)(g * DK + (t >> 3)) * NTOK + b * S_LEN + scol;

  lds_load16(kp, smem + t * 8);
  lds_load16(vp, smem + 4096 + t * 8);
  __syncthreads();

  const int kloff0 = lr * 64 + ((lg * 8) ^ ((lr & 7) << 3));
  const int kloff1 = lr * 64 + ((32 + lg * 8) ^ ((lr & 7) << 3));
  __bf16* Pw = smem + 16384 + w * 1280;  // [32][40]

  const __bf16 one1 = (__bf16)1.0f;
  const v8bf16 ones = { one1, one1, one1, one1, one1, one1, one1, one1 };
  const f32x4 fz = {0.f, 0.f, 0.f, 0.f};
  f32x4 o[2][4], o_sum[2];
  o_sum[0] = fz; o_sum[1] = fz;
#pragma unroll
  for (int mi = 0; mi < 2; mi++)
#pragma unroll
    for (int nd = 0; nd < 4; nd++) o[mi][nd] = fz;

#pragma unroll 2
  for (int kt = 0; kt < 32; kt++) {
    if (kt < 31) {
      __bf16* nb = smem + ((kt & 1) ^ 1) * 8192;
      lds_load16(kp + (size_t)64 * NQKV, nb + t * 8);
      lds_load16(vp + 64, nb + 4096 + t * 8);
      kp += (size_t)64 * NQKV;
      vp += 64;
    }
    const __bf16* Kb = smem + (kt & 1) * 8192;
    const __bf16* k0 = Kb + kloff0;
    const __bf16* k1 = Kb + kloff1;

    f32x4 st[4][2];
#pragma unroll
    for (int ni = 0; ni < 4; ni++) { st[ni][0] = fz; st[ni][1] = fz; }
    __builtin_amdgcn_s_setprio(1);
#pragma unroll
    for (int ni = 0; ni < 4; ni++) {
      v8bf16 kb = *(const v8bf16*)(k0 + ni * 1024);
      st[ni][0] = __builtin_amdgcn_mfma_f32_16x16x32_bf16(kb, qa[0][0], st[ni][0], 0, 0, 0);
      st[ni][1] = __builtin_amdgcn_mfma_f32_16x16x32_bf16(kb, qa[1][0], st[ni][1], 0, 0, 0);
    }
#pragma unroll
    for (int ni = 0; ni < 4; ni++) {
      v8bf16 kb = *(const v8bf16*)(k1 + ni * 1024);
      st[ni][0] = __builtin_amdgcn_mfma_f32_16x16x32_bf16(kb, qa[0][1], st[ni][0], 0, 0, 0);
      st[ni][1] = __builtin_amdgcn_mfma_f32_16x16x32_bf16(kb, qa[1][1], st[ni][1], 0, 0, 0);
    }
    __builtin_amdgcn_s_setprio(0);

#pragma unroll
    for (int ks = 0; ks < 2; ks++) {
      const __bf16* vbase = (ks ? k1 : k0) + 4096;
#pragma unroll
      for (int mi = 0; mi < 2; mi++)
#pragma unroll
        for (int ni2 = 0; ni2 < 2; ni2++) {
          f32x4 sv = st[2 * ks + ni2][mi];
          bf16x4 pk = { (__bf16)exp2f(sv[0]), (__bf16)exp2f(sv[1]),
                        (__bf16)exp2f(sv[2]), (__bf16)exp2f(sv[3]) };
          *(bf16x4*)(Pw + (mi * 16 + lr) * 40 + ni2 * 16 + lg * 4) = pk;
        }
      v8bf16 pa0 = *(const v8bf16*)(Pw + lr * 40 + lg * 8);
      v8bf16 pa1 = *(const v8bf16*)(Pw + (16 + lr) * 40 + lg * 8);
      __builtin_amdgcn_s_setprio(1);
#pragma unroll
      for (int nd = 0; nd < 4; nd++) {
        v8bf16 vb = *(const v8bf16*)(vbase + nd * 1024);
        o[0][nd] = __builtin_amdgcn_mfma_f32_16x16x32_bf16(pa0, vb, o[0][nd], 0, 0, 0);
        o[1][nd] = __builtin_amdgcn_mfma_f32_16x16x32_bf16(pa1, vb, o[1][nd], 0, 0, 0);
      }
      o_sum[0] = __builtin_amdgcn_mfma_f32_16x16x32_bf16(pa0, ones, o_sum[0], 0, 0, 0);
      o_sum[1] = __builtin_amdgcn_mfma_f32_16x16x32_bf16(pa1, ones, o_sum[1], 0, 0, 0);
      __builtin_amdgcn_s_setprio(0);
    }

    __syncthreads();
  }

#pragma unroll
  for (int mi = 0; mi < 2; mi++)
#pragma unroll
    for (int r = 0; r < 4; r++) {
      float inv = 1.0f / o_sum[mi][r];
      int row = b * S_LEN + q0 + w * 32 + mi * 16 + lg * 4 + r;
#pragma unroll
      for (int nd = 0; nd < 4; nd++)
        ctx[(size_t)row * D_MODEL + h * DK + nd * 16 + lr] = (__bf16)(o[mi][nd][r] * inv);
    }
}

extern "C" void kernel_launch(void* const* d_in, const int* in_sizes, int n_in,
                              void* d_out, int out_size, void* d_ws, size_t ws_size,
                              hipStream_t stream) {
  (void)in_sizes; (void)n_in; (void)out_size; (void)ws_size;
  const float* x  = (const float*)d_in[0];
  const float* wq = (const float*)d_in[1];
  const float* bq = (const float*)d_in[2];
  const float* wk = (const float*)d_in[3];
  const float* bk = (const float*)d_in[4];
  const float* wv = (const float*)d_in[5];
  const float* bv = (const float*)d_in[6];
  const float* wo = (const float*)d_in[7];
  const float* bo = (const float*)d_in[8];

  char* ws = (char*)d_ws;
  __bf16* xb    = (__bf16*)(ws);                 // [4096][2048]   16 MB
  __bf16* wqkvT = (__bf16*)(ws + 16777216);      // [3072][2048]   12 MB
  __bf16* woT   = (__bf16*)(ws + 29360128);      // [2048][2048]    8 MB
  __bf16* QKVb  = (__bf16*)(ws + 37748736);      // [4096][3072]   24 MB
  __bf16* VbT   = (__bf16*)(ws + 62914560);      // [512][4096]     4 MB
  __bf16* ctx   = (__bf16*)(ws + 67108864);      // [4096][2048]   16 MB

  dim3 tb(32, 8);
  cvt_f32_bf16<<<8192, 256, 0, stream>>>(x, xb, NTOK * D_MODEL);
  transpose_cvt_all<<<dim3(64, 64, 4), tb, 0, stream>>>(wq, wk, wv, wo, wqkvT, woT);

  gemm_big<0, 192><<<dim3(256), 512, 0, stream>>>(xb, wqkvT, bq, bk, bv,
                                                  QKVb, nullptr, VbT, NTOK, NQKV, 2048);
  attn_kernel<<<dim3(8, 64), 512, 0, stream>>>(QKVb, VbT, ctx);
  gemm_big<1, 128><<<dim3(256), 512, 0, stream>>>(ctx, woT, bo, nullptr, nullptr,
                                                  nullptr, (float*)d_out, nullptr, NTOK, 2048, 2048);
}

// Round 17
// 214.383 us; speedup vs baseline: 1.8567x; 1.0031x over previous
//
#include <hip/hip_runtime.h>
#include <hip/hip_bf16.h>

typedef __bf16 v8bf16 __attribute__((ext_vector_type(8)));
typedef __bf16 bf16x4 __attribute__((ext_vector_type(4)));
typedef float  f32x4  __attribute__((ext_vector_type(4)));

#define D_MODEL 2048
#define S_LEN   2048
#define NHEADS  32
#define NGROUPS 8
#define DK      64
#define NTOK    4096   // B*S
#define NQKV    3072   // 2048 + 512 + 512
// 0.125 (1/sqrt(64)) * log2(e): softmax done in base-2 domain
#define QSCALE  0.18033688011112042f

__device__ __forceinline__ void lds_load16(const void* g, void* l) {
  __builtin_amdgcn_global_load_lds(
      (__attribute__((address_space(1))) unsigned int*)g,
      (__attribute__((address_space(3))) unsigned int*)l, 16, 0, 0);
}

// XOR swizzle for [*][64] bf16 tiles (128B row stride): col ^= (row&7)<<3
__device__ __forceinline__ int sw64(int row, int col) {
  return row * 64 + (col ^ ((row & 7) << 3));
}

// ---------------- fp32 -> bf16 elementwise (grid-stride, 2048 blocks) ----------------
__global__ __launch_bounds__(256)
void cvt_f32_bf16(const float* __restrict__ in, __bf16* __restrict__ out, int n) {
  for (int i = (blockIdx.x * 256 + threadIdx.x) * 4; i < n; i += 2048 * 256 * 4) {
    float4 v = *(const float4*)(in + i);
    bf16x4 o = { (__bf16)v.x, (__bf16)v.y, (__bf16)v.z, (__bf16)v.w };
    *(bf16x4*)(out + i) = o;
  }
}

// ---------------- all 4 weight transposes in one launch (packed bf16x4 stores) --------
__global__ __launch_bounds__(256)
void transpose_cvt_all(const float* __restrict__ wq, const float* __restrict__ wk,
                       const float* __restrict__ wv, const float* __restrict__ wo,
                       __bf16* __restrict__ wqkvT, __bf16* __restrict__ woT) {
  __shared__ float tile[32][33];   // [src_row][src_col]
  const int tx = threadIdx.x, ty = threadIdx.y;  // 32 x 8
  const float* in;
  __bf16* out;
  int C;
  const int z = blockIdx.z;
  if (z == 0)      { in = wq; out = wqkvT;              C = 2048; }
  else if (z == 1) { if (blockIdx.x >= 16) return; in = wk; out = wqkvT + 2048 * 2048; C = 512; }
  else if (z == 2) { if (blockIdx.x >= 16) return; in = wv; out = wqkvT + 2560 * 2048; C = 512; }
  else             { in = wo; out = woT;                C = 2048; }
  const int R = 2048;
  int c0 = blockIdx.x * 32, r0 = blockIdx.y * 32;
#pragma unroll
  for (int j = 0; j < 4; j++)
    tile[ty + 8 * j][tx] = in[(size_t)(r0 + ty + 8 * j) * C + c0 + tx];
  __syncthreads();
  // packed store: thread q -> output row c0+orow (src col), 4 consecutive src rows
  const int q = ty * 32 + tx;
  const int orow = q >> 3, oq = q & 7;
  bf16x4 pk = { (__bf16)tile[oq * 4 + 0][orow], (__bf16)tile[oq * 4 + 1][orow],
                (__bf16)tile[oq * 4 + 2][orow], (__bf16)tile[oq * 4 + 3][orow] };
  *(bf16x4*)(out + (size_t)(c0 + orow) * R + r0 + oq * 4) = pk;
}

// ---------------- 4-phase GEMM: C = A * BT^T + bias ----------------
// MODE 0 additionally writes the V block (cols >= 2560) TRANSPOSED into Vt
// ([512][4096], Vt[col-2560][row]) as packed bf16x4 row-quads (fused V-transpose).
template <int MODE, int BN>
__global__ __launch_bounds__(512, 1)
void gemm_big(const __bf16* __restrict__ A, const __bf16* __restrict__ BT,
              const float* __restrict__ b0, const float* __restrict__ b1,
              const float* __restrict__ b2,
              __bf16* __restrict__ Cb, float* __restrict__ Cf,
              __bf16* __restrict__ Vt,
              int M, int N, int K) {
  constexpr int FN = BN / 64;
  __shared__ __bf16 Alds[2 * 256 * 64];
  __shared__ __bf16 Blds[3 * BN * 64];
  const int t = threadIdx.x;
  const int lane = t & 63, w = t >> 6;
  const int lr = lane & 15, lg = lane >> 4;
  const int wm = w >> 2, wn = w & 3;
  const int cpx = gridDim.x >> 3;
  const int swz = (blockIdx.x & 7) * cpx + (blockIdx.x >> 3);
  const int nbx = N / BN;
  const int m0 = (swz / nbx) * 256, n0 = (swz % nbx) * BN;
  const int scol = (((t & 7) ^ ((t >> 3) & 7)) << 3);

  const __bf16* Abase = A + (size_t)(m0 + (t >> 3)) * K + scol;
  const __bf16* Bbase = BT + (size_t)(n0 + (t >> 3)) * K + scol;

  auto stageA = [&](int tile, int c) {
    lds_load16(Abase + (size_t)(c * 64) * K + tile * 64,
               Alds + (tile & 1) * 16384 + c * 4096 + t * 8);
  };
  auto stageB = [&](int tile, int bi, int c) {
    lds_load16(Bbase + (size_t)(c * 64) * K + tile * 64,
               Blds + bi * (BN * 64) + c * 4096 + t * 8);
  };

  const f32x4 fz = {0.f, 0.f, 0.f, 0.f};
  f32x4 acc[8][FN];
#pragma unroll
  for (int fm = 0; fm < 8; fm++)
#pragma unroll
    for (int fn = 0; fn < FN; fn++) acc[fm][fn] = fz;

#pragma unroll
  for (int c = 0; c < 4; c++) stageA(0, c);
#pragma unroll
  for (int c = 0; c < FN; c++) stageB(0, 0, c);
  stageA(1, 0);
  stageA(1, 2);
#pragma unroll
  for (int c = 0; c < FN; c++) stageB(1, 1, c);

  int bcur = 0, bn1 = 1, bn2 = 2;
  for (int kt = 0; kt < 32; kt++) {
    if (kt < 31) {
      if constexpr (FN == 3) asm volatile("s_waitcnt vmcnt(5)" ::: "memory");
      else                   asm volatile("s_waitcnt vmcnt(4)" ::: "memory");
    } else {
      asm volatile("s_waitcnt vmcnt(0)" ::: "memory");
    }
    __builtin_amdgcn_s_barrier();
    __builtin_amdgcn_sched_barrier(0);

    const __bf16* Ab = Alds + (kt & 1) * 16384;
    const __bf16* Bb = Blds + bcur * (BN * 64);
    v8bf16 bfr[2][FN];

    // ---- phase 1: fmh=0, ks=0 ----
    {
#pragma unroll
      for (int fn = 0; fn < FN; fn++)
        bfr[0][fn] = *(const v8bf16*)&Bb[sw64(wn * (BN / 4) + fn * 16 + lr, lg * 8)];
      v8bf16 af[4];
#pragma unroll
      for (int j = 0; j < 4; j++)
        af[j] = *(const v8bf16*)&Ab[sw64(wm * 128 + j * 16 + lr, lg * 8)];
      if (kt < 31) stageA(kt + 1, 1);
      __builtin_amdgcn_s_barrier();
      __builtin_amdgcn_sched_barrier(0);
      __builtin_amdgcn_s_setprio(1);
#pragma unroll
      for (int j = 0; j < 4; j++)
#pragma unroll
        for (int fn = 0; fn < FN; fn++)
          acc[j][fn] = __builtin_amdgcn_mfma_f32_16x16x32_bf16(af[j], bfr[0][fn], acc[j][fn], 0, 0, 0);
      __builtin_amdgcn_s_setprio(0);
      __builtin_amdgcn_sched_barrier(0);
      __builtin_amdgcn_s_barrier();
    }
    // ---- phase 2: fmh=0, ks=1 ----
    {
#pragma unroll
      for (int fn = 0; fn < FN; fn++)
        bfr[1][fn] = *(const v8bf16*)&Bb[sw64(wn * (BN / 4) + fn * 16 + lr, 32 + lg * 8)];
      v8bf16 af[4];
#pragma unroll
      for (int j = 0; j < 4; j++)
        af[j] = *(const v8bf16*)&Ab[sw64(wm * 128 + j * 16 + lr, 32 + lg * 8)];
      if (kt < 31) stageA(kt + 1, 3);
      __builtin_amdgcn_s_barrier();
      __builtin_amdgcn_sched_barrier(0);
      __builtin_amdgcn_s_setprio(1);
#pragma unroll
      for (int j = 0; j < 4; j++)
#pragma unroll
        for (int fn = 0; fn < FN; fn++)
          acc[j][fn] = __builtin_amdgcn_mfma_f32_16x16x32_bf16(af[j], bfr[1][fn], acc[j][fn], 0, 0, 0);
      __builtin_amdgcn_s_setprio(0);
      __builtin_amdgcn_sched_barrier(0);
      __builtin_amdgcn_s_barrier();
    }
    // ---- phase 3: fmh=1, ks=0 ----
    {
      v8bf16 af[4];
#pragma unroll
      for (int j = 0; j < 4; j++)
        af[j] = *(const v8bf16*)&Ab[sw64(wm * 128 + 64 + j * 16 + lr, lg * 8)];
      if (kt < 30) { stageA(kt + 2, 0); stageB(kt + 2, bn2, 0); }
      __builtin_amdgcn_s_barrier();
      __builtin_amdgcn_sched_barrier(0);
      __builtin_amdgcn_s_setprio(1);
#pragma unroll
      for (int j = 0; j < 4; j++)
#pragma unroll
        for (int fn = 0; fn < FN; fn++)
          acc[4 + j][fn] = __builtin_amdgcn_mfma_f32_16x16x32_bf16(af[j], bfr[0][fn], acc[4 + j][fn], 0, 0, 0);
      __builtin_amdgcn_s_setprio(0);
      __builtin_amdgcn_sched_barrier(0);
      __builtin_amdgcn_s_barrier();
    }
    // ---- phase 4: fmh=1, ks=1 ----
    {
      v8bf16 af[4];
#pragma unroll
      for (int j = 0; j < 4; j++)
        af[j] = *(const v8bf16*)&Ab[sw64(wm * 128 + 64 + j * 16 + lr, 32 + lg * 8)];
      if (kt < 30) {
        stageA(kt + 2, 2);
        stageB(kt + 2, bn2, 1);
        if constexpr (FN == 3) stageB(kt + 2, bn2, 2);
      }
      __builtin_amdgcn_s_barrier();
      __builtin_amdgcn_sched_barrier(0);
      __builtin_amdgcn_s_setprio(1);
#pragma unroll
      for (int j = 0; j < 4; j++)
#pragma unroll
        for (int fn = 0; fn < FN; fn++)
          acc[4 + j][fn] = __builtin_amdgcn_mfma_f32_16x16x32_bf16(af[j], bfr[1][fn], acc[4 + j][fn], 0, 0, 0);
      __builtin_amdgcn_s_setprio(0);
      __builtin_amdgcn_sched_barrier(0);
    }

    int tmp = bcur; bcur = bn1; bn1 = bn2; bn2 = tmp;
  }

#pragma unroll
  for (int fn = 0; fn < FN; fn++) {
    int col = n0 + wn * (BN / 4) + fn * 16 + lr;
    if (MODE == 0 && col >= 2560) {
      float bias = b2[col - 2560];
#pragma unroll
      for (int fm = 0; fm < 8; fm++) {
        int row0 = m0 + wm * 128 + fm * 16 + lg * 4;
        bf16x4 pk = { (__bf16)(acc[fm][fn][0] + bias), (__bf16)(acc[fm][fn][1] + bias),
                      (__bf16)(acc[fm][fn][2] + bias), (__bf16)(acc[fm][fn][3] + bias) };
        *(bf16x4*)(Vt + (size_t)(col - 2560) * NTOK + row0) = pk;
      }
      continue;
    }
    float bias, scale = 1.0f;
    if (MODE == 0) {
      if (col < 2048) { bias = b0[col]; scale = QSCALE; }
      else            { bias = b1[col - 2048]; }
    } else {
      bias = b0[col];
    }
#pragma unroll
    for (int fm = 0; fm < 8; fm++)
#pragma unroll
      for (int r = 0; r < 4; r++) {
        int row = m0 + wm * 128 + fm * 16 + lg * 4 + r;
        float v = acc[fm][fn][r] + bias;
        if (MODE == 0) Cb[(size_t)row * N + col] = (__bf16)(v * scale);
        else           Cf[(size_t)row * N + col] = v;
      }
  }
}

// ---------------- GQA flash attention (8 waves x 32 q, r13 best-measured) ----------------
__global__ __launch_bounds__(512, 2)
void attn_kernel(const __bf16* __restrict__ QKV, const __bf16* __restrict__ VT,
                 __bf16* __restrict__ ctx) {
  __shared__ __bf16 smem[26624];
  const int t = threadIdx.x;
  const int lane = t & 63, w = t >> 6;
  const int lr = lane & 15, lg = lane >> 4;
  const int flat = blockIdx.y * 8 + blockIdx.x;
  const int swz = (flat & 7) * 64 + (flat >> 3);
  const int qt = swz & 7, bh = swz >> 3;
  const int b = bh >> 5, h = bh & 31, g = h >> 2;
  const int q0 = qt * 256;
  const int scol = (((t & 7) ^ ((t >> 3) & 7)) << 3);

  v8bf16 qa[2][2];
#pragma unroll
  for (int mi = 0; mi < 2; mi++)
#pragma unroll
    for (int dk2 = 0; dk2 < 2; dk2++)
      qa[mi][dk2] = *(const v8bf16*)(QKV +
          (size_t)(b * S_LEN + q0 + w * 32 + mi * 16 + lr) * NQKV + h * DK + dk2 * 32 + lg * 8);

  const __bf16* kp = QKV + (size_t)(b * S_LEN + (t >> 3)) * NQKV + D_MODEL + g * DK + scol;
  const __bf16* vp = VT + (size_t)(g * DK + (t >> 3)) * NTOK + b * S_LEN + scol;

  lds_load16(kp, smem + t * 8);
  lds_load16(vp, smem + 4096 + t * 8);
  __syncthreads();

  const int kloff0 = lr * 64 + ((lg * 8) ^ ((lr & 7) << 3));
  const int kloff1 = lr * 64 + ((32 + lg * 8) ^ ((lr & 7) << 3));
  __bf16* Pw = smem + 16384 + w * 1280;  // [32][40]

  const __bf16 one1 = (__bf16)1.0f;
  const v8bf16 ones = { one1, one1, one1, one1, one1, one1, one1, one1 };
  const f32x4 fz = {0.f, 0.f, 0.f, 0.f};
  f32x4 o[2][4], o_sum[2];
  o_sum[0] = fz; o_sum[1] = fz;
#pragma unroll
  for (int mi = 0; mi < 2; mi++)
#pragma unroll
    for (int nd = 0; nd < 4; nd++) o[mi][nd] = fz;

#pragma unroll 2
  for (int kt = 0; kt < 32; kt++) {
    if (kt < 31) {
      __bf16* nb = smem + ((kt & 1) ^ 1) * 8192;
      lds_load16(kp + (size_t)64 * NQKV, nb + t * 8);
      lds_load16(vp + 64, nb + 4096 + t * 8);
      kp += (size_t)64 * NQKV;
      vp += 64;
    }
    const __bf16* Kb = smem + (kt & 1) * 8192;
    const __bf16* k0 = Kb + kloff0;
    const __bf16* k1 = Kb + kloff1;

    f32x4 st[4][2];
#pragma unroll
    for (int ni = 0; ni < 4; ni++) { st[ni][0] = fz; st[ni][1] = fz; }
    __builtin_amdgcn_s_setprio(1);
#pragma unroll
    for (int ni = 0; ni < 4; ni++) {
      v8bf16 kb = *(const v8bf16*)(k0 + ni * 1024);
      st[ni][0] = __builtin_amdgcn_mfma_f32_16x16x32_bf16(kb, qa[0][0], st[ni][0], 0, 0, 0);
      st[ni][1] = __builtin_amdgcn_mfma_f32_16x16x32_bf16(kb, qa[1][0], st[ni][1], 0, 0, 0);
    }
#pragma unroll
    for (int ni = 0; ni < 4; ni++) {
      v8bf16 kb = *(const v8bf16*)(k1 + ni * 1024);
      st[ni][0] = __builtin_amdgcn_mfma_f32_16x16x32_bf16(kb, qa[0][1], st[ni][0], 0, 0, 0);
      st[ni][1] = __builtin_amdgcn_mfma_f32_16x16x32_bf16(kb, qa[1][1], st[ni][1], 0, 0, 0);
    }
    __builtin_amdgcn_s_setprio(0);

#pragma unroll
    for (int ks = 0; ks < 2; ks++) {
      const __bf16* vbase = (ks ? k1 : k0) + 4096;
#pragma unroll
      for (int mi = 0; mi < 2; mi++)
#pragma unroll
        for (int ni2 = 0; ni2 < 2; ni2++) {
          f32x4 sv = st[2 * ks + ni2][mi];
          bf16x4 pk = { (__bf16)exp2f(sv[0]), (__bf16)exp2f(sv[1]),
                        (__bf16)exp2f(sv[2]), (__bf16)exp2f(sv[3]) };
          *(bf16x4*)(Pw + (mi * 16 + lr) * 40 + ni2 * 16 + lg * 4) = pk;
        }
      v8bf16 pa0 = *(const v8bf16*)(Pw + lr * 40 + lg * 8);
      v8bf16 pa1 = *(const v8bf16*)(Pw + (16 + lr) * 40 + lg * 8);
      __builtin_amdgcn_s_setprio(1);
#pragma unroll
      for (int nd = 0; nd < 4; nd++) {
        v8bf16 vb = *(const v8bf16*)(vbase + nd * 1024);
        o[0][nd] = __builtin_amdgcn_mfma_f32_16x16x32_bf16(pa0, vb, o[0][nd], 0, 0, 0);
        o[1][nd] = __builtin_amdgcn_mfma_f32_16x16x32_bf16(pa1, vb, o[1][nd], 0, 0, 0);
      }
      o_sum[0] = __builtin_amdgcn_mfma_f32_16x16x32_bf16(pa0, ones, o_sum[0], 0, 0, 0);
      o_sum[1] = __builtin_amdgcn_mfma_f32_16x16x32_bf16(pa1, ones, o_sum[1], 0, 0, 0);
      __builtin_amdgcn_s_setprio(0);
    }

    __syncthreads();
  }

#pragma unroll
  for (int mi = 0; mi < 2; mi++)
#pragma unroll
    for (int r = 0; r < 4; r++) {
      float inv = 1.0f / o_sum[mi][r];
      int row = b * S_LEN + q0 + w * 32 + mi * 16 + lg * 4 + r;
#pragma unroll
      for (int nd = 0; nd < 4; nd++)
        ctx[(size_t)row * D_MODEL + h * DK + nd * 16 + lr] = (__bf16)(o[mi][nd][r] * inv);
    }
}

extern "C" void kernel_launch(void* const* d_in, const int* in_sizes, int n_in,
                              void* d_out, int out_size, void* d_ws, size_t ws_size,
                              hipStream_t stream) {
  (void)in_sizes; (void)n_in; (void)out_size; (void)ws_size;
  const float* x  = (const float*)d_in[0];
  const float* wq = (const float*)d_in[1];
  const float* bq = (const float*)d_in[2];
  const float* wk = (const float*)d_in[3];
  const float* bk = (const float*)d_in[4];
  const float* wv = (const float*)d_in[5];
  const float* bv = (const float*)d_in[6];
  const float* wo = (const float*)d_in[7];
  const float* bo = (const float*)d_in[8];

  char* ws = (char*)d_ws;
  __bf16* xb    = (__bf16*)(ws);                 // [4096][2048]   16 MB
  __bf16* wqkvT = (__bf16*)(ws + 16777216);      // [3072][2048]   12 MB
  __bf16* woT   = (__bf16*)(ws + 29360128);      // [2048][2048]    8 MB
  __bf16* QKVb  = (__bf16*)(ws + 37748736);      // [4096][3072]   24 MB
  __bf16* VbT   = (__bf16*)(ws + 62914560);      // [512][4096]     4 MB
  __bf16* ctx   = (__bf16*)(ws + 67108864);      // [4096][2048]   16 MB

  dim3 tb(32, 8);
  cvt_f32_bf16<<<2048, 256, 0, stream>>>(x, xb, NTOK * D_MODEL);
  transpose_cvt_all<<<dim3(64, 64, 4), tb, 0, stream>>>(wq, wk, wv, wo, wqkvT, woT);

  gemm_big<0, 192><<<dim3(256), 512, 0, stream>>>(xb, wqkvT, bq, bk, bv,
                                                  QKVb, nullptr, VbT, NTOK, NQKV, 2048);
  attn_kernel<<<dim3(8, 64), 512, 0, stream>>>(QKVb, VbT, ctx);
  gemm_big<1, 128><<<dim3(256), 512, 0, stream>>>(ctx, woT, bo, nullptr, nullptr,
                                                  nullptr, (float*)d_out, nullptr, NTOK, 2048, 2048);
}